// Round 4
// baseline (800.881 us; speedup 1.0000x reference)
//
#include <hip/hip_runtime.h>

// CRF forward (partition fn), B=512, T=512, L=102 (start=100, stop=101).
// R11: replace v_dot2_f32_f16 with v_pk_fma_f32.
// Evidence: R8 (8 chains) == R9 (interleaved shadow) == R10 (16 chains)
// within noise => dot phase insensitive to chain depth AND scheduling =>
// throughput-limited instruction, not latency. Budget: 1400cy/step measured,
// ~150cy accounted issue => ~1250cy stall ~= 104 fdot2 x ~12cy. Theory:
// fdot2 is a slow (~12cy) op on gfx950 (ISA doc lists no v_dot2; f32 peak
// spec REQUIRES full-rate v_pk_fma_f32: 256CUx128lanesx2x2x2.4G=157.3TF).
// So: Mhat now f32 float2 pairs (204 VGPRs, fine at 1 wave/SIMD),
// Q f32 in LDS (26 b128 broadcast reads), 102 pk_fma per step.
// Linear-domain recurrence (unchanged math, strictly better precision):
//   Q_t[j] = E_j(t) * sum_k Mhat[j,k] Q_{t-1}[k] * rcp(R)*2^-8
// One wave per batch element, zero s_barriers.

typedef float f32x2 __attribute__((ext_vector_type(2)));
typedef float f32x4 __attribute__((ext_vector_type(4)));

#define CRF_L 102
#define CRF_RP 104
#define CRF_START 100
#define CRF_STOP 101
#define NEG_BIG (-1.0e30f)
#define LN2F 0.6931471805599453f

template <int CTRL>
__device__ __forceinline__ float dpp_add_step(float x) {
    int xi = __builtin_bit_cast(int, x);
    int yi = __builtin_amdgcn_update_dpp(0, xi, CTRL, 0xf, 0xf, true);
    return x + __builtin_bit_cast(float, yi);
}
__device__ __forceinline__ float wave_sum64(float v) {
    v = dpp_add_step<0x111>(v);  // row_shr:1
    v = dpp_add_step<0x112>(v);  // row_shr:2
    v = dpp_add_step<0x114>(v);  // row_shr:4
    v = dpp_add_step<0x118>(v);  // row_shr:8
    v = dpp_add_step<0x142>(v);  // row_bcast:15
    v = dpp_add_step<0x143>(v);  // row_bcast:31
    return __builtin_bit_cast(float,
        __builtin_amdgcn_readlane(__builtin_bit_cast(int, v), 63));
}

__attribute__((amdgpu_waves_per_eu(1, 1)))
__launch_bounds__(64)
__global__ void crf_forward_kernel(const float* __restrict__ logits,
                                   const float* __restrict__ trans,
                                   const int* __restrict__ lens,
                                   float* __restrict__ out,
                                   int B, int T) {
    const int b    = blockIdx.x;
    const int lane = threadIdx.x;          // 0..63
    const int r0   = 2 * lane;
    const int r1   = 2 * lane + 1;
    const bool valid = (lane < 51);        // rows 0..101

    __shared__ __align__(16) float TS[CRF_L * CRF_RP];   // trans, padded rows
    __shared__ __align__(16) float Qf[104];              // 26 float4 read span

    // ---- stage trans into LDS (coalesced, setup-only) ----
    #pragma unroll 4
    for (int r = 0; r < CRF_L; ++r)
        for (int c = lane; c < CRF_L; c += 64)
            TS[CRF_RP * r + c] = trans[CRF_L * r + c];

    // ---- init Q (all 104 slots; Q0 = onehot(START)) ----
    if (lane < 52) {
        int i0 = 2 * lane;
        Qf[i0]     = (i0 == CRF_START) ? 1.f : 0.f;
        Qf[i0 + 1] = 0.f;
    }
    __builtin_amdgcn_wave_barrier();

    // ---- rowmax + pack Mhat = exp(trans - rowmax) into 2x52 f32 pairs ----
    const float* rowA = &TS[CRF_RP * (valid ? r0 : 0)];
    const float* rowB = &TS[CRF_RP * (valid ? r1 : 0)];
    float rmax0 = NEG_BIG, rmax1 = NEG_BIG;
    #pragma unroll
    for (int k = 0; k < CRF_L; ++k) {
        rmax0 = fmaxf(rmax0, rowA[k]);
        rmax1 = fmaxf(rmax1, rowB[k]);
    }

    f32x2 mA2[52], mB2[52];
    #pragma unroll
    for (int i = 0; i < 51; ++i) {
        mA2[i] = (f32x2){__expf(rowA[2*i]   - rmax0),
                         __expf(rowA[2*i+1] - rmax0)};
        mB2[i] = (f32x2){__expf(rowB[2*i]   - rmax1),
                         __expf(rowB[2*i+1] - rmax1)};
    }
    mA2[51] = (f32x2){0.f, 0.f};   // k = 102,103 pad
    mB2[51] = (f32x2){0.f, 0.f};

    // E uses logit + rowmax; invalid rows get -inf so E==0 (q stays 0)
    const float erm0 = (valid)               ? rmax0 : NEG_BIG;
    const float erm1 = (valid && r1 < CRF_L) ? rmax1 : NEG_BIG;

    const int len = min(lens[b], T);
    const float* lg = logits + (size_t)b * (size_t)T * (size_t)CRF_L;
    const int loff = valid ? r0 : 0;

    // depth-3 logit prefetch: lgA = logits[t], lgB = [t+1], lgC = [t+2]
    float2 lgA = *reinterpret_cast<const float2*>(lg + loff);
    float2 lgB = *reinterpret_cast<const float2*>(lg + (size_t)min(1, T - 1) * CRF_L + loff);
    float2 lgC = *reinterpret_cast<const float2*>(lg + (size_t)min(2, T - 1) * CRF_L + loff);

    // q registers hold q_{t-1} entering iteration t; start = onehot(START).
    float q0 = (r0 == CRF_START) ? 1.f : 0.f;
    float q1 = 0.f;
    float Lacc = 0.f;
    const int sidx = min(r0, 102);   // lanes >=51 alias the zero pad (benign)

    for (int t = 0; t < len; ++t) {
        // ---- dot(Mhat[r,:], Q[:]) both rows: 26 b128 broadcasts,
        //      102 v_pk_fma_f32 (4 chains of f32x2, 2 per row) ----
        const f32x4* P4 = reinterpret_cast<const f32x4*>(&Qf[0]);
        f32x2 aA0 = {0.f, 0.f}, aA1 = {0.f, 0.f};
        f32x2 aB0 = {0.f, 0.f}, aB1 = {0.f, 0.f};
        #pragma unroll
        for (int j = 0; j < 26; ++j) {
            f32x4 qv = P4[j];
            f32x2 qlo = (f32x2){qv[0], qv[1]};
            f32x2 qhi = (f32x2){qv[2], qv[3]};
            aA0 = __builtin_elementwise_fma(mA2[2*j],     qlo, aA0);
            aA1 = __builtin_elementwise_fma(mA2[2*j + 1], qhi, aA1);
            aB0 = __builtin_elementwise_fma(mB2[2*j],     qlo, aB0);
            aB1 = __builtin_elementwise_fma(mB2[2*j + 1], qhi, aB1);
        }

        // ---- shadow work (single scheduling region; compiler interleaves) --
        float s = q0 + q1;                 // wave-sum of q_{t-1}
        s = dpp_add_step<0x111>(s);
        s = dpp_add_step<0x112>(s);
        s = dpp_add_step<0x114>(s);
        s = dpp_add_step<0x118>(s);
        s = dpp_add_step<0x142>(s);
        s = dpp_add_step<0x143>(s);
        float R = __builtin_bit_cast(float,
            __builtin_amdgcn_readlane(__builtin_bit_cast(int, s), 63));
        R = fmaxf(R, 1e-30f);
        float invRs = __builtin_amdgcn_rcpf(R) * 0.00390625f;  // rcp(R)*2^-8
        float l2R = __log2f(R);
        float ecx = __expf(lgA.x + erm0);  // E for THIS step t
        float ecy = __expf(lgA.y + erm1);

        lgA = lgB; lgB = lgC;              // rotate prefetch pipeline
        lgC = *reinterpret_cast<const float2*>(
            lg + (size_t)min(t + 3, T - 1) * CRF_L + loff);

        f32x2 tA = aA0 + aA1;
        f32x2 tB = aB0 + aB1;
        float dot0 = tA[0] + tA[1];
        float dot1 = tB[0] + tB[1];

        // ---- linear-domain update (factor R*2^8 logged; +8 folded to end) --
        Lacc += l2R;
        q0 = (dot0 * ecx) * invRs;
        q1 = (dot1 * ecy) * invRs;

        __builtin_amdgcn_wave_barrier();   // keep write below all dot reads
        *reinterpret_cast<f32x2*>(&Qf[sidx]) = (f32x2){q0, q1};
        __builtin_amdgcn_wave_barrier();
    }

    // ---- epilogue: out = ln2*(Lacc+8*len) + log(sum_j Q_j exp(trans[STOP,j]))
    float ts0 = TS[CRF_RP * CRF_STOP + (valid ? r0 : 0)];
    float ts1 = TS[CRF_RP * CRF_STOP + (valid ? r1 : 0)];
    float e;
    if (len == 0) {
        e = ((r0 == CRF_START) ? __expf(ts0) : 0.f);   // Q0 = onehot(START)
    } else {
        e = q0 * __expf(ts0) + q1 * __expf(ts1);       // invalid lanes: q=0
    }
    float se = wave_sum64(e);

    if (lane == 0)
        out[b] = LN2F * (Lacc + 8.0f * (float)len) + __logf(se);
}

extern "C" void kernel_launch(void* const* d_in, const int* in_sizes, int n_in,
                              void* d_out, int out_size, void* d_ws, size_t ws_size,
                              hipStream_t stream) {
    const float* logits = (const float*)d_in[0];   // [B, T, L] fp32
    const float* trans  = (const float*)d_in[1];   // [L, L] fp32
    const int*   lens   = (const int*)d_in[2];     // [B] int32
    float* out = (float*)d_out;                    // [B] fp32

    const int B = 512;
    const int T = 512;

    crf_forward_kernel<<<dim3(B), dim3(64), 0, stream>>>(
        logits, trans, lens, out, B, T);
}

// Round 5
// 789.605 us; speedup vs baseline: 1.0143x; 1.0143x over previous
//
#include <hip/hip_runtime.h>

// CRF forward (partition fn), B=512, T=512, L=102 (start=100, stop=101).
// R12: R11's pk_fma idea, implemented so M actually lives in REGISTERS.
// R11 post-mortem: VGPR_Count stayed 132 => mA2[]/mB2[] arrays went to
// scratch (rule: indexed ext_vector arrays may be demoted); dur 2.1x worse,
// VALUBusy 4.7% = scratch-latency-bound. Fix: 104 NAMED f32x2 variables
// (REP26 macros, same pattern that kept R8's 104 half2s in VGPRs).
// Dot phase: 26 b128 Q broadcasts + 104 v_pk_fma_f32 in 8 chains (depth 13).
// Verification handle: VGPR_Count must be ~240-256, else spilled again.
// Linear-domain recurrence (unchanged):
//   Q_t[j] = E_j(t) * sum_k Mhat[j,k] Q_{t-1}[k] * rcp(R)*2^-8
// One wave per batch element, zero s_barriers.

typedef float f32x2 __attribute__((ext_vector_type(2)));
typedef float f32x4 __attribute__((ext_vector_type(4)));

#define CRF_L 102
#define CRF_RP 104
#define CRF_START 100
#define CRF_STOP 101
#define NEG_BIG (-1.0e30f)
#define LN2F 0.6931471805599453f

#define REP26(X) X(0) X(1) X(2) X(3) X(4) X(5) X(6) X(7) X(8) X(9) X(10) \
                 X(11) X(12) X(13) X(14) X(15) X(16) X(17) X(18) X(19) X(20) \
                 X(21) X(22) X(23) X(24) X(25)

template <int CTRL>
__device__ __forceinline__ float dpp_add_step(float x) {
    int xi = __builtin_bit_cast(int, x);
    int yi = __builtin_amdgcn_update_dpp(0, xi, CTRL, 0xf, 0xf, true);
    return x + __builtin_bit_cast(float, yi);
}
__device__ __forceinline__ float wave_sum64(float v) {
    v = dpp_add_step<0x111>(v);  // row_shr:1
    v = dpp_add_step<0x112>(v);  // row_shr:2
    v = dpp_add_step<0x114>(v);  // row_shr:4
    v = dpp_add_step<0x118>(v);  // row_shr:8
    v = dpp_add_step<0x142>(v);  // row_bcast:15
    v = dpp_add_step<0x143>(v);  // row_bcast:31
    return __builtin_bit_cast(float,
        __builtin_amdgcn_readlane(__builtin_bit_cast(int, v), 63));
}

__device__ __forceinline__ f32x2 mk2f(const float* rowp, int k, float rmx) {
    float e0 = (k + 0 < CRF_L) ? __expf(rowp[k + 0] - rmx) : 0.f;
    float e1 = (k + 1 < CRF_L) ? __expf(rowp[k + 1] - rmx) : 0.f;
    return (f32x2){e0, e1};
}

__attribute__((amdgpu_waves_per_eu(1, 1)))
__launch_bounds__(64)
__global__ void crf_forward_kernel(const float* __restrict__ logits,
                                   const float* __restrict__ trans,
                                   const int* __restrict__ lens,
                                   float* __restrict__ out,
                                   int B, int T) {
    const int b    = blockIdx.x;
    const int lane = threadIdx.x;          // 0..63
    const int r0   = 2 * lane;
    const int r1   = 2 * lane + 1;
    const bool valid = (lane < 51);        // rows 0..101

    __shared__ __align__(16) float TS[CRF_L * CRF_RP];   // trans, padded rows
    __shared__ __align__(16) float Qf[104];              // 26 float4 read span

    // ---- stage trans into LDS (coalesced, setup-only) ----
    #pragma unroll 4
    for (int r = 0; r < CRF_L; ++r)
        for (int c = lane; c < CRF_L; c += 64)
            TS[CRF_RP * r + c] = trans[CRF_L * r + c];

    // ---- init Q (all 104 slots; Q0 = onehot(START)) ----
    if (lane < 52) {
        int i0 = 2 * lane;
        Qf[i0]     = (i0 == CRF_START) ? 1.f : 0.f;
        Qf[i0 + 1] = 0.f;
    }
    __builtin_amdgcn_wave_barrier();

    // ---- rowmax + pack Mhat = exp(trans - rowmax), 104 NAMED f32x2 regs ----
    const float* rowA = &TS[CRF_RP * (valid ? r0 : 0)];
    const float* rowB = &TS[CRF_RP * (valid ? r1 : 0)];
    float rmax0 = NEG_BIG, rmax1 = NEG_BIG;
    #pragma unroll
    for (int k = 0; k < CRF_L; ++k) {
        rmax0 = fmaxf(rmax0, rowA[k]);
        rmax1 = fmaxf(rmax1, rowB[k]);
    }

#define DECLM(j) f32x2 ma##j##_0, ma##j##_1, mb##j##_0, mb##j##_1;
    REP26(DECLM)
#undef DECLM
#define PACKJ(j) \
    ma##j##_0 = mk2f(rowA, 4*(j)+0, rmax0); ma##j##_1 = mk2f(rowA, 4*(j)+2, rmax0); \
    mb##j##_0 = mk2f(rowB, 4*(j)+0, rmax1); mb##j##_1 = mk2f(rowB, 4*(j)+2, rmax1);
    REP26(PACKJ)
#undef PACKJ

    // E uses logit + rowmax; invalid rows get -inf so E==0 (q stays 0)
    const float erm0 = (valid)               ? rmax0 : NEG_BIG;
    const float erm1 = (valid && r1 < CRF_L) ? rmax1 : NEG_BIG;

    const int len = min(lens[b], T);
    const float* lg = logits + (size_t)b * (size_t)T * (size_t)CRF_L;
    const int loff = valid ? r0 : 0;

    // depth-3 logit prefetch: lgA = logits[t], lgB = [t+1], lgC = [t+2]
    float2 lgA = *reinterpret_cast<const float2*>(lg + loff);
    float2 lgB = *reinterpret_cast<const float2*>(lg + (size_t)min(1, T - 1) * CRF_L + loff);
    float2 lgC = *reinterpret_cast<const float2*>(lg + (size_t)min(2, T - 1) * CRF_L + loff);

    // q registers hold q_{t-1} entering iteration t; start = onehot(START).
    float q0 = (r0 == CRF_START) ? 1.f : 0.f;
    float q1 = 0.f;
    float Lacc = 0.f;
    const int sidx = min(r0, 102);   // lanes >=51 alias the zero pad (benign)

    for (int t = 0; t < len; ++t) {
        // ---- dot(Mhat[r,:], Q[:]) both rows: 26 b128 broadcasts,
        //      104 v_pk_fma_f32 in 8 chains (j-parity split, depth 13) ----
        const f32x4* P4 = reinterpret_cast<const f32x4*>(&Qf[0]);
        f32x2 aA0 = {0.f, 0.f}, aA1 = {0.f, 0.f};
        f32x2 aA2 = {0.f, 0.f}, aA3 = {0.f, 0.f};
        f32x2 aB0 = {0.f, 0.f}, aB1 = {0.f, 0.f};
        f32x2 aB2 = {0.f, 0.f}, aB3 = {0.f, 0.f};
#define DOTQ(j, AA0, AA1, BB0, BB1) { f32x4 qv = P4[j]; \
        f32x2 qlo = (f32x2){qv[0], qv[1]}; \
        f32x2 qhi = (f32x2){qv[2], qv[3]}; \
        AA0 = __builtin_elementwise_fma(ma##j##_0, qlo, AA0); \
        AA1 = __builtin_elementwise_fma(ma##j##_1, qhi, AA1); \
        BB0 = __builtin_elementwise_fma(mb##j##_0, qlo, BB0); \
        BB1 = __builtin_elementwise_fma(mb##j##_1, qhi, BB1); }
        DOTQ(0,  aA0, aA1, aB0, aB1)
        DOTQ(1,  aA2, aA3, aB2, aB3)
        DOTQ(2,  aA0, aA1, aB0, aB1)
        DOTQ(3,  aA2, aA3, aB2, aB3)
        DOTQ(4,  aA0, aA1, aB0, aB1)
        DOTQ(5,  aA2, aA3, aB2, aB3)
        DOTQ(6,  aA0, aA1, aB0, aB1)
        DOTQ(7,  aA2, aA3, aB2, aB3)
        DOTQ(8,  aA0, aA1, aB0, aB1)
        DOTQ(9,  aA2, aA3, aB2, aB3)
        DOTQ(10, aA0, aA1, aB0, aB1)
        DOTQ(11, aA2, aA3, aB2, aB3)
        DOTQ(12, aA0, aA1, aB0, aB1)
        DOTQ(13, aA2, aA3, aB2, aB3)
        DOTQ(14, aA0, aA1, aB0, aB1)
        DOTQ(15, aA2, aA3, aB2, aB3)
        DOTQ(16, aA0, aA1, aB0, aB1)
        DOTQ(17, aA2, aA3, aB2, aB3)
        DOTQ(18, aA0, aA1, aB0, aB1)
        DOTQ(19, aA2, aA3, aB2, aB3)
        DOTQ(20, aA0, aA1, aB0, aB1)
        DOTQ(21, aA2, aA3, aB2, aB3)
        DOTQ(22, aA0, aA1, aB0, aB1)
        DOTQ(23, aA2, aA3, aB2, aB3)
        DOTQ(24, aA0, aA1, aB0, aB1)
        DOTQ(25, aA2, aA3, aB2, aB3)
#undef DOTQ

        // ---- shadow work (same scheduling region; compiler interleaves) ----
        float s = q0 + q1;                 // wave-sum of q_{t-1}
        s = dpp_add_step<0x111>(s);
        s = dpp_add_step<0x112>(s);
        s = dpp_add_step<0x114>(s);
        s = dpp_add_step<0x118>(s);
        s = dpp_add_step<0x142>(s);
        s = dpp_add_step<0x143>(s);
        float R = __builtin_bit_cast(float,
            __builtin_amdgcn_readlane(__builtin_bit_cast(int, s), 63));
        R = fmaxf(R, 1e-30f);
        float invRs = __builtin_amdgcn_rcpf(R) * 0.00390625f;  // rcp(R)*2^-8
        float l2R = __log2f(R);
        float ecx = __expf(lgA.x + erm0);  // E for THIS step t
        float ecy = __expf(lgA.y + erm1);

        lgA = lgB; lgB = lgC;              // rotate prefetch pipeline
        lgC = *reinterpret_cast<const float2*>(
            lg + (size_t)min(t + 3, T - 1) * CRF_L + loff);

        f32x2 tA = (aA0 + aA2) + (aA1 + aA3);
        f32x2 tB = (aB0 + aB2) + (aB1 + aB3);
        float dot0 = tA[0] + tA[1];
        float dot1 = tB[0] + tB[1];

        // ---- linear-domain update (factor R*2^8 logged; +8 folded to end) --
        Lacc += l2R;
        q0 = (dot0 * ecx) * invRs;
        q1 = (dot1 * ecy) * invRs;

        __builtin_amdgcn_wave_barrier();   // keep write below all dot reads
        *reinterpret_cast<f32x2*>(&Qf[sidx]) = (f32x2){q0, q1};
        __builtin_amdgcn_wave_barrier();
    }

    // ---- epilogue: out = ln2*(Lacc+8*len) + log(sum_j Q_j exp(trans[STOP,j]))
    float ts0 = TS[CRF_RP * CRF_STOP + (valid ? r0 : 0)];
    float ts1 = TS[CRF_RP * CRF_STOP + (valid ? r1 : 0)];
    float e;
    if (len == 0) {
        e = ((r0 == CRF_START) ? __expf(ts0) : 0.f);   // Q0 = onehot(START)
    } else {
        e = q0 * __expf(ts0) + q1 * __expf(ts1);       // invalid lanes: q=0
    }
    float se = wave_sum64(e);

    if (lane == 0)
        out[b] = LN2F * (Lacc + 8.0f * (float)len) + __logf(se);
}

extern "C" void kernel_launch(void* const* d_in, const int* in_sizes, int n_in,
                              void* d_out, int out_size, void* d_ws, size_t ws_size,
                              hipStream_t stream) {
    const float* logits = (const float*)d_in[0];   // [B, T, L] fp32
    const float* trans  = (const float*)d_in[1];   // [L, L] fp32
    const int*   lens   = (const int*)d_in[2];     // [B] int32
    float* out = (float*)d_out;                    // [B] fp32

    const int B = 512;
    const int T = 512;

    crf_forward_kernel<<<dim3(B), dim3(64), 0, stream>>>(
        logits, trans, lens, out, B, T);
}

// Round 6
// 377.563 us; speedup vs baseline: 2.1212x; 2.0913x over previous
//
#include <hip/hip_runtime.h>

// CRF forward (partition fn), B=512, T=512, L=102 (start=100, stop=101).
// R13: 2-wave row split so f32 M fits registers (R11/R12 post-mortem:
// compiler refuses >~132 VGPR for this kernel; 208-reg M spilled to
// scratch both times => restructure under the budget instead).
//   - 128 thr/block: wave0 rows 0-50, wave1 rows 51-101, ONE row/lane.
//   - M = 51 named f32x2 per lane (~104 VGPR) -> guaranteed resident.
//   - dot: 51 v_pk_fma_f32 in 8 chains; Q f32 in LDS, 26 b128 broadcasts.
//   - R = sum q_{t-1}: wave-partial sums live in Q's pad slots [102],[103],
//     read by the SAME j=25 b128 the dot already does (pad coeff dropped
//     from the fma, so pads never enter the math). No DPP on the path.
//   - double-buffered Q + one __syncthreads per step.
//   - trans read from global at setup (no TS LDS): bank conflicts ~0.
// Linear recurrence (same math as R8, f32 all the way):
//   Q_t[j] = E_j(t) * sum_k Mhat[j,k] Q_{t-1}[k] * rcp(R)*2^-8
// Verification handles: VGPR ~140 (132=>spilled), LDS ~1KB, conflicts ~0.

typedef float f32x2 __attribute__((ext_vector_type(2)));
typedef float f32x4 __attribute__((ext_vector_type(4)));

#define CRF_L 102
#define CRF_RP 104
#define CRF_START 100
#define CRF_STOP 101
#define NEG_BIG (-1.0e30f)
#define LN2F 0.6931471805599453f

#define REP25(X) X(0) X(1) X(2) X(3) X(4) X(5) X(6) X(7) X(8) X(9) X(10) \
                 X(11) X(12) X(13) X(14) X(15) X(16) X(17) X(18) X(19) \
                 X(20) X(21) X(22) X(23) X(24)

template <int CTRL>
__device__ __forceinline__ float dpp_add_step(float x) {
    int xi = __builtin_bit_cast(int, x);
    int yi = __builtin_amdgcn_update_dpp(0, xi, CTRL, 0xf, 0xf, true);
    return x + __builtin_bit_cast(float, yi);
}
__device__ __forceinline__ float wave_sum64(float v) {
    v = dpp_add_step<0x111>(v);  // row_shr:1
    v = dpp_add_step<0x112>(v);  // row_shr:2
    v = dpp_add_step<0x114>(v);  // row_shr:4
    v = dpp_add_step<0x118>(v);  // row_shr:8
    v = dpp_add_step<0x142>(v);  // row_bcast:15
    v = dpp_add_step<0x143>(v);  // row_bcast:31
    return __builtin_bit_cast(float,
        __builtin_amdgcn_readlane(__builtin_bit_cast(int, v), 63));
}

__device__ __forceinline__ f32x2 mk2f(const float* rowp, int k, float rmx) {
    float e0 = __expf(rowp[k + 0] - rmx);
    float e1 = __expf(rowp[k + 1] - rmx);
    return (f32x2){e0, e1};
}

__attribute__((amdgpu_waves_per_eu(1, 1)))
__launch_bounds__(128)
__global__ void crf_forward_kernel(const float* __restrict__ logits,
                                   const float* __restrict__ trans,
                                   const int* __restrict__ lens,
                                   float* __restrict__ out,
                                   int B, int T) {
    const int b    = blockIdx.x;
    const int tid  = threadIdx.x;          // 0..127
    const int wv   = tid >> 6;             // wave 0/1
    const int lane = tid & 63;
    const bool active = (lane < 51);
    const int r    = 51 * wv + lane;       // row 0..101 for active lanes

    // Q double-buffer: [p][0..101]=q values, [p][102]=S_wave0, [p][103]=S_wave1
    __shared__ __align__(16) float Qbuf[2][CRF_RP];

    // ---- init Qbuf[0] = onehot(START); slots = {1,0} (R(0)=1) ----
    if (tid < 51) {
        int i0 = 2 * tid;
        Qbuf[0][i0]     = (i0 == CRF_START) ? 1.f : 0.f;
        Qbuf[0][i0 + 1] = 0.f;
    }
    if (tid == 0) { Qbuf[0][102] = 1.f; Qbuf[0][103] = 0.f; }

    // ---- per-lane row of Mhat = exp(trans[r,:] - rowmax) in 51 f32x2 regs --
    const float* rowp = trans + (size_t)CRF_L * (active ? r : 0);
    float rmx = NEG_BIG;
    #pragma unroll
    for (int k = 0; k < CRF_L; ++k) rmx = fmaxf(rmx, rowp[k]);

#define DECLM(j) f32x2 m##j##a, m##j##b;
    REP25(DECLM)
#undef DECLM
    f32x2 m25a;
#define PACKJ(j) m##j##a = mk2f(rowp, 4*(j), rmx); \
                 m##j##b = mk2f(rowp, 4*(j)+2, rmx);
    REP25(PACKJ)
#undef PACKJ
    m25a = mk2f(rowp, 100, rmx);           // k = 100,101 (no pad pair)

    // E = exp(logit + rmx); inactive lanes forced to 0 via -inf bias
    const float erm = active ? rmx : NEG_BIG;

    const int len = min(lens[b], T);
    const float* lgp = logits + (size_t)b * (size_t)T * (size_t)CRF_L
                              + (active ? r : 0);

    // depth-3 scalar logit prefetch
    float lgA = lgp[0];
    float lgB = lgp[(size_t)min(1, T - 1) * CRF_L];
    float lgC = lgp[(size_t)min(2, T - 1) * CRF_L];

    float q    = 0.f;
    float Lacc = 0.f;

    __syncthreads();                       // init visible to both waves

    for (int t = 0; t < len; ++t) {
        const int cur = t & 1;
        const f32x4* P4 = reinterpret_cast<const f32x4*>(&Qbuf[cur][0]);

        // ---- R from pad slots (part of the j=25 b128 we need anyway) ----
        f32x4 qv25 = P4[25];
        float R = qv25[2] + qv25[3];       // S_w0 + S_w1 = sum q_{t-1}
        R = fmaxf(R, 1e-30f);
        float invRs = __builtin_amdgcn_rcpf(R) * 0.00390625f;  // rcp(R)*2^-8
        float l2R = __log2f(R);

        // ---- dot(Mhat[r,:], Q): 26 b128 broadcasts, 51 pk_fma, 8 chains ----
        f32x2 aL0 = {0.f,0.f}, aL1 = {0.f,0.f}, aL2 = {0.f,0.f}, aL3 = {0.f,0.f};
        f32x2 aH0 = {0.f,0.f}, aH1 = {0.f,0.f}, aH2 = {0.f,0.f}, aH3 = {0.f,0.f};
#define DOTQ(j, AL, AH) { f32x4 qv_ = P4[j]; \
        AL = __builtin_elementwise_fma(m##j##a, (f32x2){qv_[0], qv_[1]}, AL); \
        AH = __builtin_elementwise_fma(m##j##b, (f32x2){qv_[2], qv_[3]}, AH); }
        DOTQ(0,  aL0, aH0) DOTQ(1,  aL1, aH1) DOTQ(2,  aL2, aH2) DOTQ(3,  aL3, aH3)
        DOTQ(4,  aL0, aH0) DOTQ(5,  aL1, aH1) DOTQ(6,  aL2, aH2) DOTQ(7,  aL3, aH3)
        DOTQ(8,  aL0, aH0) DOTQ(9,  aL1, aH1) DOTQ(10, aL2, aH2) DOTQ(11, aL3, aH3)
        DOTQ(12, aL0, aH0) DOTQ(13, aL1, aH1) DOTQ(14, aL2, aH2) DOTQ(15, aL3, aH3)
        DOTQ(16, aL0, aH0) DOTQ(17, aL1, aH1) DOTQ(18, aL2, aH2) DOTQ(19, aL3, aH3)
        DOTQ(20, aL0, aH0) DOTQ(21, aL1, aH1) DOTQ(22, aL2, aH2) DOTQ(23, aL3, aH3)
        DOTQ(24, aL0, aH0)
#undef DOTQ
        // group 25: k=100,101 only (pad slots carry S, coeff dropped)
        aL1 = __builtin_elementwise_fma(m25a, (f32x2){qv25[0], qv25[1]}, aL1);

        // ---- shadow: E for this step, prefetch rotate ----
        float ec = __expf(lgA + erm);
        lgA = lgB; lgB = lgC;
        lgC = lgp[(size_t)min(t + 3, T - 1) * CRF_L];

        f32x2 tL = (aL0 + aL1) + (aL2 + aL3);
        f32x2 tH = (aH0 + aH1) + (aH2 + aH3);
        f32x2 tt = tL + tH;
        float dot = tt[0] + tt[1];

        // ---- linear-domain update (factor R*2^8 logged; +8 folded to end) --
        Lacc += l2R;
        q = (dot * ec) * invRs;            // inactive lanes: ec=0 => q=0

        float* Qn = &Qbuf[cur ^ 1][0];
        if (active) Qn[r] = q;

        // wave-partial sum for next step's R (inactive q=0)
        float S = wave_sum64(q);
        if (lane == 0) Qn[102 + wv] = S;

        __syncthreads();                   // writes visible; reads drained
    }

    // ---- epilogue: out = ln2*(Lacc+8*len) + log(sum_j q_j exp(trans[STOP,j]))
    float tsr = trans[CRF_L * CRF_STOP + (active ? r : 0)];
    float e;
    if (len == 0) {
        e = (active && r == CRF_START) ? __expf(tsr) : 0.f;  // Q0=onehot
    } else {
        e = q * __expf(tsr);               // inactive lanes: q=0
    }
    float sw = wave_sum64(e);
    if (lane == 0) Qbuf[0][wv] = sw;
    __syncthreads();
    if (tid == 0)
        out[b] = LN2F * (Lacc + 8.0f * (float)len)
               + __logf(Qbuf[0][0] + Qbuf[0][1]);
}

extern "C" void kernel_launch(void* const* d_in, const int* in_sizes, int n_in,
                              void* d_out, int out_size, void* d_ws, size_t ws_size,
                              hipStream_t stream) {
    const float* logits = (const float*)d_in[0];   // [B, T, L] fp32
    const float* trans  = (const float*)d_in[1];   // [L, L] fp32
    const int*   lens   = (const int*)d_in[2];     // [B] int32
    float* out = (float*)d_out;                    // [B] fp32

    const int B = 512;
    const int T = 512;

    crf_forward_kernel<<<dim3(B), dim3(128), 0, stream>>>(
        logits, trans, lens, out, B, T);
}